// Round 1
// baseline (234.868 us; speedup 1.0000x reference)
//
#include <hip/hip_runtime.h>
#include <math.h>

#define NUM_GRAPHS 48
#define F 128
#define BM 32
#define SLICES 8

__device__ __forceinline__ float softplus_f(float x) {
    // matches jax.nn.softplus = logaddexp(x, 0)
    return fmaxf(x, 0.0f) + log1pf(expf(-fabsf(x)));
}
__device__ __forceinline__ float silu_f(float x) {
    return x / (1.0f + expf(-x));
}

__global__ void init_kernel(float* q_sum, float* cnt, double* e_acc) {
    int t = threadIdx.x;
    if (t < NUM_GRAPHS) { q_sum[t] = 0.0f; cnt[t] = 0.0f; }
    if (t == 0) *e_acc = 0.0;
}

// batch is sorted; seg[g] = first index with batch[i] >= g; seg[NUM_GRAPHS] = N
__global__ void seg_kernel(const int* __restrict__ batch, int* __restrict__ seg, int N) {
    int i = blockIdx.x * blockDim.x + threadIdx.x;
    if (i >= N) return;
    int b = batch[i];
    int prev = (i == 0) ? -1 : batch[i - 1];
    for (int g = prev + 1; g <= b; ++g) seg[g] = i;
    if (i == N - 1) {
        for (int g = b + 1; g <= NUM_GRAPHS; ++g) seg[g] = N;
    }
}

// Fused dual-head MLP: q_raw = SiLU(h0@qW1+qb1)@qW2 ; vdw = SiLU(h0@vW1+vb1)@vW2+vb2
// Block: 256 threads, BM=32 atoms. Thread (a = tid>>3, s = tid&7) computes
// hidden cols j0..j0+15 (j0 = 16*s) for atom a, both heads, then the 8 s-threads
// shuffle-reduce the second-layer partial sums.
__global__ __launch_bounds__(256) void mlp_kernel(
    const float* __restrict__ h0,
    const float* __restrict__ qW1, const float* __restrict__ qb1,
    const float* __restrict__ qW2,
    const float* __restrict__ vW1, const float* __restrict__ vb1,
    const float* __restrict__ vW2, const float* __restrict__ vb2,
    const int* __restrict__ batch,
    float* __restrict__ q_raw, float* __restrict__ c6, float* __restrict__ rv,
    float* __restrict__ q_sum, float* __restrict__ cnt, int N)
{
    __shared__ float h0s[BM][F + 4];   // +4 pad: bank = (4a+k)%32 -> conflict-free broadcast
    const int tid = threadIdx.x;
    const int a0 = blockIdx.x * BM;

    for (int idx = tid; idx < BM * (F / 4); idx += 256) {
        int a = idx >> 5;          // 32 float4 per row
        int kq = idx & 31;
        int row = a0 + a;
        float4 v = make_float4(0.f, 0.f, 0.f, 0.f);
        if (row < N) v = ((const float4*)(h0 + (size_t)row * F))[kq];
        ((float4*)&h0s[a][0])[kq] = v;
    }
    __syncthreads();

    const int a  = tid >> 3;
    const int s  = tid & 7;
    const int j0 = s * 16;

    float accq[16], accv[16];
    #pragma unroll
    for (int m = 0; m < 16; ++m) { accq[m] = qb1[j0 + m]; accv[m] = vb1[j0 + m]; }

    for (int k4 = 0; k4 < F / 4; ++k4) {
        float4 hv = ((const float4*)&h0s[a][0])[k4];
        float h[4] = {hv.x, hv.y, hv.z, hv.w};
        #pragma unroll
        for (int u = 0; u < 4; ++u) {
            int k = k4 * 4 + u;
            const float4* qr = (const float4*)(qW1 + k * F + j0);
            const float4* vr = (const float4*)(vW1 + k * F + j0);
            #pragma unroll
            for (int m4 = 0; m4 < 4; ++m4) {
                float4 wq = qr[m4], wv = vr[m4];
                accq[m4*4+0] = fmaf(h[u], wq.x, accq[m4*4+0]);
                accq[m4*4+1] = fmaf(h[u], wq.y, accq[m4*4+1]);
                accq[m4*4+2] = fmaf(h[u], wq.z, accq[m4*4+2]);
                accq[m4*4+3] = fmaf(h[u], wq.w, accq[m4*4+3]);
                accv[m4*4+0] = fmaf(h[u], wv.x, accv[m4*4+0]);
                accv[m4*4+1] = fmaf(h[u], wv.y, accv[m4*4+1]);
                accv[m4*4+2] = fmaf(h[u], wv.z, accv[m4*4+2]);
                accv[m4*4+3] = fmaf(h[u], wv.w, accv[m4*4+3]);
            }
        }
    }

    float pq = 0.f, p0 = 0.f, p1 = 0.f;
    #pragma unroll
    for (int m = 0; m < 16; ++m) {
        int j = j0 + m;
        float sq = silu_f(accq[m]);
        pq = fmaf(sq, qW2[j], pq);
        float sv = silu_f(accv[m]);
        p0 = fmaf(sv, vW2[2*j],     p0);
        p1 = fmaf(sv, vW2[2*j + 1], p1);
    }
    // reduce across the 8 s-threads (contiguous 8-aligned lane groups)
    #pragma unroll
    for (int d = 4; d >= 1; d >>= 1) {
        pq += __shfl_xor(pq, d);
        p0 += __shfl_xor(p0, d);
        p1 += __shfl_xor(p1, d);
    }
    int row = a0 + a;
    if (s == 0 && row < N) {
        q_raw[row] = pq;
        int b = batch[row];
        atomicAdd(&q_sum[b], pq);
        atomicAdd(&cnt[b], 1.0f);
        c6[row] = softplus_f(p0 + vb2[0]);
        rv[row] = softplus_f(p1 + vb2[1]);
    }
}

// One wave per (graph, row-slice). Lanes sweep j within the graph's segment.
__global__ __launch_bounds__(64) void pair_kernel(
    const float* __restrict__ pos,
    const float* __restrict__ q_raw,
    const float* __restrict__ c6a, const float* __restrict__ rva,
    const float* __restrict__ q_sum, const float* __restrict__ cnt,
    const int* __restrict__ seg, const float* __restrict__ sigma_p,
    double* __restrict__ e_acc)
{
    int g     = blockIdx.x / SLICES;
    int slice = blockIdx.x % SLICES;
    int lane  = threadIdx.x;
    int s0 = seg[g], s1 = seg[g + 1];
    double acc = 0.0;
    if (s1 > s0) {
        float mean  = q_sum[g] / fmaxf(cnt[g], 1.0f);
        float inv_ss = 1.0f / (1.41421356f * sigma_p[0]);
        for (int i = s0 + slice; i < s1; i += SLICES) {
            float xi = pos[3*i+0], yi = pos[3*i+1], zi = pos[3*i+2];
            float qi  = q_raw[i] - mean;
            float c6i = c6a[i];
            float rvi = rva[i];
            for (int j = s0 + lane; j < s1; j += 64) {
                if (j == i) continue;
                float dx = xi - pos[3*j+0];
                float dy = yi - pos[3*j+1];
                float dz = zi - pos[3*j+2];
                float d2 = fmaf(dx, dx, fmaf(dy, dy, dz * dz));
                float dist = sqrtf(d2 + 1e-8f);
                float qj = q_raw[j] - mean;
                float e1 = qi * qj * erff(dist * inv_ss) / (dist + 1e-8f);
                float c6ij = sqrtf(c6i * c6a[j]);
                float rr   = rvi * rva[j];
                float damp = fmaf(d2 * d2, d2, rr * rr * rr);  // d2^3 + (r_i r_j)^3
                float e2 = c6ij / (damp + 1e-8f);
                acc += (double)((0.5f * 14.3996f) * e1 - 0.5f * e2);
            }
        }
    }
    #pragma unroll
    for (int d = 32; d >= 1; d >>= 1) acc += __shfl_xor(acc, d);
    if (lane == 0) atomicAdd(e_acc, acc);
}

__global__ void finalize_kernel(const double* __restrict__ e_acc, float* __restrict__ out) {
    if (threadIdx.x == 0) out[0] = (float)(*e_acc);   // LONG_RANGE_SCALE = 1.0
}

extern "C" void kernel_launch(void* const* d_in, const int* in_sizes, int n_in,
                              void* d_out, int out_size, void* d_ws, size_t ws_size,
                              hipStream_t stream) {
    const float* h0   = (const float*)d_in[0];
    // d_in[1] = h1 (unused on this path)
    const float* pos  = (const float*)d_in[2];
    const float* qW1  = (const float*)d_in[3];
    const float* qb1  = (const float*)d_in[4];
    const float* qW2  = (const float*)d_in[5];
    const float* sig  = (const float*)d_in[6];
    const float* vW1  = (const float*)d_in[7];
    const float* vb1  = (const float*)d_in[8];
    const float* vW2  = (const float*)d_in[9];
    const float* vb2  = (const float*)d_in[10];
    const int*  batch = (const int*)d_in[11];
    const int N = in_sizes[0] / F;   // 6144

    char* ws = (char*)d_ws;
    double* e_acc = (double*)ws;                 // 8 B
    float* q_sum  = (float*)(ws + 8);            // 48 f
    float* cnt    = (float*)(ws + 8 + 192);      // 48 f
    int*   seg    = (int*)(ws + 8 + 384);        // 49 i  (ends at 588)
    float* q_raw  = (float*)(ws + 640);          // N f
    float* c6     = q_raw + N;
    float* rv     = c6 + N;
    float* out    = (float*)d_out;

    init_kernel<<<1, 64, 0, stream>>>(q_sum, cnt, e_acc);
    seg_kernel<<<(N + 255) / 256, 256, 0, stream>>>(batch, seg, N);
    mlp_kernel<<<(N + BM - 1) / BM, 256, 0, stream>>>(
        h0, qW1, qb1, qW2, vW1, vb1, vW2, vb2, batch, q_raw, c6, rv, q_sum, cnt, N);
    pair_kernel<<<NUM_GRAPHS * SLICES, 64, 0, stream>>>(
        pos, q_raw, c6, rv, q_sum, cnt, seg, sig, e_acc);
    finalize_kernel<<<1, 64, 0, stream>>>(e_acc, out);
}

// Round 2
// 118.424 us; speedup vs baseline: 1.9833x; 1.9833x over previous
//
#include <hip/hip_runtime.h>
#include <math.h>

#define NUM_GRAPHS 48
#define F 128
#define MB 16        // atoms per MLP block
#define SLICES 32    // row-slices per graph in pair kernel
#define NPART (NUM_GRAPHS * SLICES)

__device__ __forceinline__ float softplus_f(float x) {
    return fmaxf(x, 0.0f) + log1pf(expf(-fabsf(x)));
}
__device__ __forceinline__ float silu_f(float x) {
    return x / (1.0f + expf(-x));
}

// batch is sorted; seg[g] = first index with batch[i] >= g; seg[NUM_GRAPHS] = N
__global__ void seg_kernel(const int* __restrict__ batch, int* __restrict__ seg, int N) {
    int i = blockIdx.x * blockDim.x + threadIdx.x;
    if (i >= N) return;
    int b = batch[i];
    int prev = (i == 0) ? -1 : batch[i - 1];
    for (int g = prev + 1; g <= b; ++g) seg[g] = i;
    if (i == N - 1) {
        for (int g = b + 1; g <= NUM_GRAPHS; ++g) seg[g] = N;
    }
}

// Fused dual-head MLP, weight-coalesced layout.
// Block: 256 threads = 2 groups of 128. Thread (g2 = tid>>7, j = tid&127)
// computes hidden column j for 8 atoms (group g2's half of the 16-atom tile),
// both heads. Weight reads W1[k][j] are coalesced across the 128 j-threads;
// h0 comes from LDS via same-address broadcast reads (conflict-free).
__global__ __launch_bounds__(256) void mlp_kernel(
    const float* __restrict__ h0,
    const float* __restrict__ qW1, const float* __restrict__ qb1,
    const float* __restrict__ qW2,
    const float* __restrict__ vW1, const float* __restrict__ vb1,
    const float* __restrict__ vW2, const float* __restrict__ vb2,
    float* __restrict__ q_raw, float* __restrict__ c6, float* __restrict__ rv,
    int N)
{
    __shared__ float h0s[MB][F];
    __shared__ float red[4][8][3];   // [wave][atom-in-group][pq,p0,p1]
    const int tid = threadIdx.x;
    const int a0 = blockIdx.x * MB;

    // stage 16 atom rows (8 KB), coalesced float4
    for (int idx = tid; idx < MB * (F / 4); idx += 256) {
        int a = idx >> 5;          // 32 float4 per row
        int kq = idx & 31;
        int row = a0 + a;
        float4 v = make_float4(0.f, 0.f, 0.f, 0.f);
        if (row < N) v = ((const float4*)(h0 + (size_t)row * F))[kq];
        ((float4*)&h0s[a][0])[kq] = v;
    }
    __syncthreads();

    const int j  = tid & 127;
    const int g2 = tid >> 7;

    float accq[8], accv[8];
    const float qb = qb1[j], vb = vb1[j];
    #pragma unroll
    for (int a = 0; a < 8; ++a) { accq[a] = qb; accv[a] = vb; }

    const float* __restrict__ qc = qW1 + j;
    const float* __restrict__ vc = vW1 + j;

    #pragma unroll 2
    for (int k4 = 0; k4 < F / 4; ++k4) {
        float wq[4], wv[4];
        #pragma unroll
        for (int u = 0; u < 4; ++u) {
            wq[u] = qc[(size_t)(k4 * 4 + u) * F];
            wv[u] = vc[(size_t)(k4 * 4 + u) * F];
        }
        #pragma unroll
        for (int a = 0; a < 8; ++a) {
            float4 hv = ((const float4*)&h0s[g2 * 8 + a][0])[k4];
            float tq = accq[a];
            tq = fmaf(hv.x, wq[0], tq);
            tq = fmaf(hv.y, wq[1], tq);
            tq = fmaf(hv.z, wq[2], tq);
            tq = fmaf(hv.w, wq[3], tq);
            accq[a] = tq;
            float tv = accv[a];
            tv = fmaf(hv.x, wv[0], tv);
            tv = fmaf(hv.y, wv[1], tv);
            tv = fmaf(hv.z, wv[2], tv);
            tv = fmaf(hv.w, wv[3], tv);
            accv[a] = tv;
        }
    }

    // second layer: per-atom reduce over j (64 lanes butterfly, then wave pair via LDS)
    const float w2q = qW2[j];
    const float w20 = vW2[2 * j];
    const float w21 = vW2[2 * j + 1];
    const int wave = tid >> 6;

    #pragma unroll
    for (int a = 0; a < 8; ++a) {
        float pq = silu_f(accq[a]) * w2q;
        float sv = silu_f(accv[a]);
        float p0 = sv * w20;
        float p1 = sv * w21;
        #pragma unroll
        for (int d = 32; d >= 1; d >>= 1) {
            pq += __shfl_xor(pq, d);
            p0 += __shfl_xor(p0, d);
            p1 += __shfl_xor(p1, d);
        }
        if ((tid & 63) == 0) {
            red[wave][a][0] = pq;
            red[wave][a][1] = p0;
            red[wave][a][2] = p1;
        }
    }
    __syncthreads();

    if (tid < MB) {
        int g  = tid >> 3;    // which wave pair
        int al = tid & 7;
        int row = a0 + tid;   // atoms 0..7 -> waves 0,1 ; atoms 8..15 -> waves 2,3
        if (row < N) {
            float pq = red[2 * g][al][0] + red[2 * g + 1][al][0];
            float p0 = red[2 * g][al][1] + red[2 * g + 1][al][1];
            float p1 = red[2 * g][al][2] + red[2 * g + 1][al][2];
            q_raw[row] = pq;
            c6[row] = softplus_f(p0 + vb2[0]);
            rv[row] = softplus_f(p1 + vb2[1]);
        }
    }
}

// One wave per (graph, row-slice). Per-block local q-mean (no atomics).
// Each block writes one float partial; finalize sums them.
__global__ __launch_bounds__(64) void pair_kernel(
    const float* __restrict__ pos,
    const float* __restrict__ q_raw,
    const float* __restrict__ c6a, const float* __restrict__ rva,
    const int* __restrict__ seg, const float* __restrict__ sigma_p,
    float* __restrict__ part)
{
    int g     = blockIdx.x / SLICES;
    int slice = blockIdx.x % SLICES;
    int lane  = threadIdx.x;
    int s0 = seg[g], s1 = seg[g + 1];
    int n = s1 - s0;
    float acc = 0.0f;
    if (n > 0) {
        // local mean of q over segment
        float ms = 0.f;
        for (int i = s0 + lane; i < s1; i += 64) ms += q_raw[i];
        #pragma unroll
        for (int d = 32; d >= 1; d >>= 1) ms += __shfl_xor(ms, d);
        float mean = ms / fmaxf((float)n, 1.0f);
        float inv_ss = 1.0f / (1.41421356f * sigma_p[0]);
        for (int i = s0 + slice; i < s1; i += SLICES) {
            float xi = pos[3*i+0], yi = pos[3*i+1], zi = pos[3*i+2];
            float qi  = q_raw[i] - mean;
            float c6i = c6a[i];
            float rvi = rva[i];
            for (int jj = s0 + lane; jj < s1; jj += 64) {
                if (jj == i) continue;
                float dx = xi - pos[3*jj+0];
                float dy = yi - pos[3*jj+1];
                float dz = zi - pos[3*jj+2];
                float d2 = fmaf(dx, dx, fmaf(dy, dy, dz * dz));
                float dist = sqrtf(d2 + 1e-8f);
                float qj = q_raw[jj] - mean;
                float e1 = qi * qj * erff(dist * inv_ss) / (dist + 1e-8f);
                float c6ij = sqrtf(c6i * c6a[jj]);
                float rr   = rvi * rva[jj];
                float damp = fmaf(d2 * d2, d2, rr * rr * rr);  // d2^3 + (r_i r_j)^3
                float e2 = c6ij / (damp + 1e-8f);
                acc += (0.5f * 14.3996f) * e1 - 0.5f * e2;
            }
        }
    }
    #pragma unroll
    for (int d = 32; d >= 1; d >>= 1) acc += __shfl_xor(acc, d);
    if (lane == 0) part[blockIdx.x] = acc;
}

__global__ __launch_bounds__(256) void finalize_kernel(
    const float* __restrict__ part, int nparts, float* __restrict__ out)
{
    __shared__ double reds[4];
    int tid = threadIdx.x;
    double s = 0.0;
    for (int i = tid; i < nparts; i += 256) s += (double)part[i];
    #pragma unroll
    for (int d = 32; d >= 1; d >>= 1) s += __shfl_xor(s, d);
    if ((tid & 63) == 0) reds[tid >> 6] = s;
    __syncthreads();
    if (tid == 0) {
        double t = reds[0] + reds[1] + reds[2] + reds[3];
        out[0] = (float)t;   // LONG_RANGE_SCALE = 1.0
    }
}

extern "C" void kernel_launch(void* const* d_in, const int* in_sizes, int n_in,
                              void* d_out, int out_size, void* d_ws, size_t ws_size,
                              hipStream_t stream) {
    const float* h0   = (const float*)d_in[0];
    // d_in[1] = h1 (unused on this path)
    const float* pos  = (const float*)d_in[2];
    const float* qW1  = (const float*)d_in[3];
    const float* qb1  = (const float*)d_in[4];
    const float* qW2  = (const float*)d_in[5];
    const float* sig  = (const float*)d_in[6];
    const float* vW1  = (const float*)d_in[7];
    const float* vb1  = (const float*)d_in[8];
    const float* vW2  = (const float*)d_in[9];
    const float* vb2  = (const float*)d_in[10];
    const int*  batch = (const int*)d_in[11];
    const int N = in_sizes[0] / F;   // 6144

    char* ws = (char*)d_ws;
    int*   seg   = (int*)ws;                       // 49 ints
    float* part  = (float*)(ws + 256);             // NPART floats
    float* q_raw = (float*)(ws + 256 + NPART * 4); // N floats
    float* c6    = q_raw + N;
    float* rv    = c6 + N;
    float* out   = (float*)d_out;

    seg_kernel<<<(N + 255) / 256, 256, 0, stream>>>(batch, seg, N);
    mlp_kernel<<<(N + MB - 1) / MB, 256, 0, stream>>>(
        h0, qW1, qb1, qW2, vW1, vb1, vW2, vb2, q_raw, c6, rv, N);
    pair_kernel<<<NPART, 64, 0, stream>>>(pos, q_raw, c6, rv, seg, sig, part);
    finalize_kernel<<<1, 256, 0, stream>>>(part, NPART, out);
}

// Round 3
// 110.120 us; speedup vs baseline: 2.1328x; 1.0754x over previous
//
#include <hip/hip_runtime.h>
#include <math.h>

#define NUM_GRAPHS 48
#define F 128
#define MB 16          // atoms per MLP block
#define R 8            // pair blocks per graph
#define NPB (NUM_GRAPHS * R)
#define CHUNK 512      // atoms staged per LDS chunk in pair kernel

__device__ __forceinline__ float softplus_f(float x) {
    return fmaxf(x, 0.0f) + log1pf(expf(-fabsf(x)));
}
__device__ __forceinline__ float silu_f(float x) {
    return x / (1.0f + expf(-x));
}

// Fused dual-head MLP + (block 0) segment-boundary scan.
// Block: 256 threads = 2 groups of 128. Thread (g2 = tid>>7, j = tid&127)
// computes hidden column j for 8 atoms, both heads. Weight reads W1[k][j]
// coalesced across j; h0 from LDS same-address broadcast (conflict-free).
// Epilogue stores q_raw, sqrt(c6), r_vdw^3 (pair kernel needs only products).
__global__ __launch_bounds__(256) void mlp_kernel(
    const float* __restrict__ h0,
    const float* __restrict__ qW1, const float* __restrict__ qb1,
    const float* __restrict__ qW2,
    const float* __restrict__ vW1, const float* __restrict__ vb1,
    const float* __restrict__ vW2, const float* __restrict__ vb2,
    const int* __restrict__ batch, int* __restrict__ seg,
    float* __restrict__ q_raw, float* __restrict__ c6s, float* __restrict__ rv3,
    int N)
{
    __shared__ float h0s[MB][F];
    __shared__ float red[4][8][3];
    const int tid = threadIdx.x;
    const int a0 = blockIdx.x * MB;

    // block 0 also computes segment boundaries (sorted batch)
    if (blockIdx.x == 0) {
        for (int i = tid; i < N; i += 256) {
            int b = batch[i];
            int prev = (i == 0) ? -1 : batch[i - 1];
            for (int g = prev + 1; g <= b; ++g) seg[g] = i;
            if (i == N - 1) {
                for (int g = b + 1; g <= NUM_GRAPHS; ++g) seg[g] = N;
            }
        }
    }

    // stage 16 atom rows (8 KB), coalesced float4
    for (int idx = tid; idx < MB * (F / 4); idx += 256) {
        int a = idx >> 5;
        int kq = idx & 31;
        int row = a0 + a;
        float4 v = make_float4(0.f, 0.f, 0.f, 0.f);
        if (row < N) v = ((const float4*)(h0 + (size_t)row * F))[kq];
        ((float4*)&h0s[a][0])[kq] = v;
    }
    __syncthreads();

    const int j  = tid & 127;
    const int g2 = tid >> 7;

    float accq[8], accv[8];
    const float qb = qb1[j], vb = vb1[j];
    #pragma unroll
    for (int a = 0; a < 8; ++a) { accq[a] = qb; accv[a] = vb; }

    const float* __restrict__ qc = qW1 + j;
    const float* __restrict__ vc = vW1 + j;

    // double-buffered weight prefetch: loads for k4+1 issue before FMAs of k4
    float wq[4], wv[4];
    #pragma unroll
    for (int u = 0; u < 4; ++u) {
        wq[u] = qc[(size_t)u * F];
        wv[u] = vc[(size_t)u * F];
    }

    #pragma unroll 2
    for (int k4 = 0; k4 < F / 4; ++k4) {
        int kn = (k4 < F / 4 - 1) ? (k4 + 1) : k4;   // clamp: last iter re-reads (discarded)
        float nq[4], nv[4];
        #pragma unroll
        for (int u = 0; u < 4; ++u) {
            nq[u] = qc[(size_t)(kn * 4 + u) * F];
            nv[u] = vc[(size_t)(kn * 4 + u) * F];
        }
        #pragma unroll
        for (int a = 0; a < 8; ++a) {
            float4 hv = ((const float4*)&h0s[g2 * 8 + a][0])[k4];
            float tq = accq[a];
            tq = fmaf(hv.x, wq[0], tq);
            tq = fmaf(hv.y, wq[1], tq);
            tq = fmaf(hv.z, wq[2], tq);
            tq = fmaf(hv.w, wq[3], tq);
            accq[a] = tq;
            float tv = accv[a];
            tv = fmaf(hv.x, wv[0], tv);
            tv = fmaf(hv.y, wv[1], tv);
            tv = fmaf(hv.z, wv[2], tv);
            tv = fmaf(hv.w, wv[3], tv);
            accv[a] = tv;
        }
        #pragma unroll
        for (int u = 0; u < 4; ++u) { wq[u] = nq[u]; wv[u] = nv[u]; }
    }

    const float w2q = qW2[j];
    const float w20 = vW2[2 * j];
    const float w21 = vW2[2 * j + 1];
    const int wave = tid >> 6;

    #pragma unroll
    for (int a = 0; a < 8; ++a) {
        float pq = silu_f(accq[a]) * w2q;
        float sv = silu_f(accv[a]);
        float p0 = sv * w20;
        float p1 = sv * w21;
        #pragma unroll
        for (int d = 32; d >= 1; d >>= 1) {
            pq += __shfl_xor(pq, d);
            p0 += __shfl_xor(p0, d);
            p1 += __shfl_xor(p1, d);
        }
        if ((tid & 63) == 0) {
            red[wave][a][0] = pq;
            red[wave][a][1] = p0;
            red[wave][a][2] = p1;
        }
    }
    __syncthreads();

    if (tid < MB) {
        int g  = tid >> 3;
        int al = tid & 7;
        int row = a0 + tid;
        if (row < N) {
            float pq = red[2 * g][al][0] + red[2 * g + 1][al][0];
            float p0 = red[2 * g][al][1] + red[2 * g + 1][al][1];
            float p1 = red[2 * g][al][2] + red[2 * g + 1][al][2];
            q_raw[row] = pq;
            c6s[row] = sqrtf(softplus_f(p0 + vb2[0]));
            float r  = softplus_f(p1 + vb2[1]);
            rv3[row] = r * r * r;
        }
    }
}

// 256 threads = 4 waves per block, R blocks per graph -> 32 row-waves/graph.
// Segment staged into LDS in CHUNK-sized pieces; inner loop is LDS+VALU only.
__global__ __launch_bounds__(256) void pair_kernel(
    const float* __restrict__ pos,
    const float* __restrict__ q_raw,
    const float* __restrict__ c6s, const float* __restrict__ rv3,
    const int* __restrict__ seg, const float* __restrict__ sigma_p,
    float* __restrict__ part)
{
    __shared__ float xs[CHUNK], ys[CHUNK], zs[CHUNK];
    __shared__ float qs[CHUNK], ss[CHUNK], r3[CHUNK];
    __shared__ float wred[4];

    const int g     = blockIdx.x / R;
    const int slice = blockIdx.x % R;
    const int tid   = threadIdx.x;
    const int wave  = tid >> 6;
    const int lane  = tid & 63;
    const int s0 = seg[g], s1 = seg[g + 1];
    const int n = s1 - s0;

    float acc = 0.0f;
    if (n > 1) {
        // per-wave (redundant) mean of q over segment — L1/L2-cached reads
        float ms = 0.f;
        for (int i = s0 + lane; i < s1; i += 64) ms += q_raw[i];
        #pragma unroll
        for (int d = 32; d >= 1; d >>= 1) ms += __shfl_xor(ms, d);
        const float mean = ms / (float)n;
        const float inv_ss = 1.0f / (1.41421356f * sigma_p[0]);
        const int wv = slice * 4 + wave;    // 0..31: this wave's row stride slot

        for (int c0 = s0; c0 < s1; c0 += CHUNK) {
            const int cn = min(CHUNK, s1 - c0);
            __syncthreads();
            for (int idx = tid; idx < cn; idx += 256) {
                int a = c0 + idx;
                xs[idx] = pos[3 * a + 0];
                ys[idx] = pos[3 * a + 1];
                zs[idx] = pos[3 * a + 2];
                qs[idx] = q_raw[a] - mean;
                ss[idx] = c6s[a];
                r3[idx] = rv3[a];
            }
            __syncthreads();

            for (int i = s0 + wv; i < s1; i += 4 * R) {
                float xi = pos[3 * i + 0], yi = pos[3 * i + 1], zi = pos[3 * i + 2];
                float qi = q_raw[i] - mean;
                float si = c6s[i];
                float ri = rv3[i];
                for (int jd = lane; jd < cn; jd += 64) {
                    if (c0 + jd == i) continue;
                    float dx = xi - xs[jd];
                    float dy = yi - ys[jd];
                    float dz = zi - zs[jd];
                    float d2 = fmaf(dx, dx, fmaf(dy, dy, dz * dz));
                    float dist = sqrtf(d2 + 1e-8f);
                    float e1 = qi * qs[jd] * erff(dist * inv_ss) / (dist + 1e-8f);
                    float damp = fmaf(d2 * d2, d2, fmaf(ri, r3[jd], 1e-8f));
                    float e2 = si * ss[jd] / damp;
                    acc += (0.5f * 14.3996f) * e1 - 0.5f * e2;
                }
            }
        }
    }
    #pragma unroll
    for (int d = 32; d >= 1; d >>= 1) acc += __shfl_xor(acc, d);
    if (n > 1) {
        if (lane == 0) wred[wave] = acc;
        __syncthreads();
        if (tid == 0) part[blockIdx.x] = wred[0] + wred[1] + wred[2] + wred[3];
    } else if (tid == 0) {
        part[blockIdx.x] = 0.0f;
    }
}

__global__ __launch_bounds__(256) void finalize_kernel(
    const float* __restrict__ part, int nparts, float* __restrict__ out)
{
    __shared__ double reds[4];
    int tid = threadIdx.x;
    double s = 0.0;
    for (int i = tid; i < nparts; i += 256) s += (double)part[i];
    #pragma unroll
    for (int d = 32; d >= 1; d >>= 1) s += __shfl_xor(s, d);
    if ((tid & 63) == 0) reds[tid >> 6] = s;
    __syncthreads();
    if (tid == 0) out[0] = (float)(reds[0] + reds[1] + reds[2] + reds[3]);
}

extern "C" void kernel_launch(void* const* d_in, const int* in_sizes, int n_in,
                              void* d_out, int out_size, void* d_ws, size_t ws_size,
                              hipStream_t stream) {
    const float* h0   = (const float*)d_in[0];
    // d_in[1] = h1 (unused on this path)
    const float* pos  = (const float*)d_in[2];
    const float* qW1  = (const float*)d_in[3];
    const float* qb1  = (const float*)d_in[4];
    const float* qW2  = (const float*)d_in[5];
    const float* sig  = (const float*)d_in[6];
    const float* vW1  = (const float*)d_in[7];
    const float* vb1  = (const float*)d_in[8];
    const float* vW2  = (const float*)d_in[9];
    const float* vb2  = (const float*)d_in[10];
    const int*  batch = (const int*)d_in[11];
    const int N = in_sizes[0] / F;   // 6144

    char* ws = (char*)d_ws;
    int*   seg   = (int*)ws;                      // 49 ints
    float* part  = (float*)(ws + 256);            // NPB floats
    float* q_raw = (float*)(ws + 256 + NPB * 4);  // N floats
    float* c6s   = q_raw + N;
    float* rv3   = c6s + N;
    float* out   = (float*)d_out;

    mlp_kernel<<<(N + MB - 1) / MB, 256, 0, stream>>>(
        h0, qW1, qb1, qW2, vW1, vb1, vW2, vb2, batch, seg, q_raw, c6s, rv3, N);
    pair_kernel<<<NPB, 256, 0, stream>>>(pos, q_raw, c6s, rv3, seg, sig, part);
    finalize_kernel<<<1, 256, 0, stream>>>(part, NPB, out);
}